// Round 1
// baseline (261.209 us; speedup 1.0000x reference)
//
#include <hip/hip_runtime.h>
#include <math.h>

// Problem dims (fixed by setup_inputs)
#define BB 16
#define HH 64
#define WW 64
#define CC 512
#define CI 64
#define NROWS (BB * HH * WW)   // 65536 rows of length C
#define LN_EPS 1e-3f

__device__ __forceinline__ float wave_sum(float v) {
#pragma unroll
  for (int m = 32; m >= 1; m >>= 1) v += __shfl_xor(v, m, 64);
  return v;
}

// ---------------------------------------------------------------------------
// K1: yf = x @ Wf, yh = x @ Wh  (K=512, N=64 each), then LayerNorm over Ci=64.
// One wave handles R1 rows. x rows are wave-uniform -> scalar loads.
// W columns: lane d reads W[c*64 + d] -> coalesced 256B vector loads.
// ---------------------------------------------------------------------------
#define R1 8
__global__ __launch_bounds__(256) void sgsa_k1_gemm_ln(
    const float* __restrict__ x, const float* __restrict__ Wf,
    const float* __restrict__ Wh, const float* __restrict__ gf,
    const float* __restrict__ bf, const float* __restrict__ gh,
    const float* __restrict__ bh, float* __restrict__ fg,
    float* __restrict__ hl) {
  const int lane = threadIdx.x & 63;
  int wid = blockIdx.x * (blockDim.x >> 6) + (threadIdx.x >> 6);
  wid = __builtin_amdgcn_readfirstlane(wid);
  const int row0 = wid * R1;
  if (row0 >= NROWS) return;

  float accf[R1], acch[R1];
#pragma unroll
  for (int r = 0; r < R1; ++r) {
    accf[r] = 0.f;
    acch[r] = 0.f;
  }

  const float* __restrict__ xrow = x + (size_t)row0 * CC;

  for (int c0 = 0; c0 < CC; c0 += 8) {
    float wfv[8], whv[8];
#pragma unroll
    for (int i = 0; i < 8; ++i) {
      wfv[i] = Wf[(c0 + i) * CI + lane];
      whv[i] = Wh[(c0 + i) * CI + lane];
    }
#pragma unroll
    for (int r = 0; r < R1; ++r) {
#pragma unroll
      for (int i = 0; i < 8; ++i) {
        float xv = xrow[r * CC + c0 + i];  // wave-uniform -> s_load
        accf[r] = fmaf(xv, wfv[i], accf[r]);
        acch[r] = fmaf(xv, whv[i], acch[r]);
      }
    }
  }

  const float gfv = gf[lane], bfvv = bf[lane];
  const float ghv = gh[lane], bhvv = bh[lane];

#pragma unroll
  for (int r = 0; r < R1; ++r) {
    // LN for f-branch
    float s = wave_sum(accf[r]);
    float q = wave_sum(accf[r] * accf[r]);
    float mean = s * (1.f / 64.f);
    float var = q * (1.f / 64.f) - mean * mean;
    float inv = rsqrtf(var + LN_EPS);
    fg[(size_t)(row0 + r) * CI + lane] = (accf[r] - mean) * inv * gfv + bfvv;
    // LN for h-branch
    float s2 = wave_sum(acch[r]);
    float q2 = wave_sum(acch[r] * acch[r]);
    float mean2 = s2 * (1.f / 64.f);
    float var2 = q2 * (1.f / 64.f) - mean2 * mean2;
    float inv2 = rsqrtf(var2 + LN_EPS);
    hl[(size_t)(row0 + r) * CI + lane] = (acch[r] - mean2) * inv2 * ghv + bhvv;
  }
}

// ---------------------------------------------------------------------------
// K2: attn = softmax over h of fg[b,w,h,d] * fg[b,h,w,d]; t = attn * hl.
// Writes t IN PLACE over hl (each element is read/written by exactly one
// thread). One block per (b,w); thread = (q = h-quarter, d).
// ---------------------------------------------------------------------------
__global__ __launch_bounds__(256) void sgsa_k2_softmax(
    const float* __restrict__ fg, float* __restrict__ hl) {
  const int bw = blockIdx.x;  // 0 .. B*W-1
  const int b = bw >> 6;
  const int w = bw & 63;
  const int d = threadIdx.x & 63;
  const int q = threadIdx.x >> 6;  // 0..3, each owns 16 h values

  float sv[16], hv[16];
#pragma unroll
  for (int i = 0; i < 16; ++i) {
    int h = q * 16 + i;
    float g = fg[(size_t)(((b * 64 + h) * 64 + w) * 64) + d];
    float f = fg[(size_t)(((b * 64 + w) * 64 + h) * 64) + d];
    sv[i] = f * g;
    hv[i] = hl[(size_t)(((b * 64 + h) * 64 + w) * 64) + d];
  }

  __shared__ float red[4][64];

  float m = sv[0];
#pragma unroll
  for (int i = 1; i < 16; ++i) m = fmaxf(m, sv[i]);
  red[q][d] = m;
  __syncthreads();
  m = fmaxf(fmaxf(red[0][d], red[1][d]), fmaxf(red[2][d], red[3][d]));
  __syncthreads();  // before red reuse

  float ssum = 0.f;
#pragma unroll
  for (int i = 0; i < 16; ++i) {
    sv[i] = __expf(sv[i] - m);
    ssum += sv[i];
  }
  red[q][d] = ssum;
  __syncthreads();
  ssum = (red[0][d] + red[1][d]) + (red[2][d] + red[3][d]);
  float rinv = 1.f / ssum;

#pragma unroll
  for (int i = 0; i < 16; ++i) {
    int h = q * 16 + i;
    hl[(size_t)(((b * 64 + h) * 64 + w) * 64) + d] = sv[i] * rinv * hv[i];
  }
}

// ---------------------------------------------------------------------------
// K3: out = LN_C( t @ Wfgh ) * scale + x.  One wave per R3 rows; lane owns
// 8 output channels (c = i*64 + lane). t row elements are wave-uniform ->
// scalar loads; Wfgh rows are coalesced vector loads.
// ---------------------------------------------------------------------------
#define R3 8
__global__ __launch_bounds__(256) void sgsa_k3_gemm_ln_res(
    const float* __restrict__ t, const float* __restrict__ Wo,
    const float* __restrict__ go, const float* __restrict__ bo,
    const float* __restrict__ scale, const float* __restrict__ x,
    float* __restrict__ out) {
  const int lane = threadIdx.x & 63;
  int wid = blockIdx.x * (blockDim.x >> 6) + (threadIdx.x >> 6);
  wid = __builtin_amdgcn_readfirstlane(wid);
  const int row0 = wid * R3;
  if (row0 >= NROWS) return;

  float acc[R3][8];
#pragma unroll
  for (int r = 0; r < R3; ++r)
#pragma unroll
    for (int i = 0; i < 8; ++i) acc[r][i] = 0.f;

  const float* __restrict__ trow = t + (size_t)row0 * CI;

  for (int d = 0; d < CI; ++d) {
    float wv[8];
#pragma unroll
    for (int i = 0; i < 8; ++i) wv[i] = Wo[d * CC + i * 64 + lane];
#pragma unroll
    for (int r = 0; r < R3; ++r) {
      float tv = trow[r * CI + d];  // wave-uniform -> s_load
#pragma unroll
      for (int i = 0; i < 8; ++i) acc[r][i] = fmaf(tv, wv[i], acc[r][i]);
    }
  }

  float gv[8], bv[8];
#pragma unroll
  for (int i = 0; i < 8; ++i) {
    gv[i] = go[i * 64 + lane];
    bv[i] = bo[i * 64 + lane];
  }
  const float sc = scale[0];

#pragma unroll
  for (int r = 0; r < R3; ++r) {
    float s = 0.f, q = 0.f;
#pragma unroll
    for (int i = 0; i < 8; ++i) {
      s += acc[r][i];
      q += acc[r][i] * acc[r][i];
    }
    s = wave_sum(s);
    q = wave_sum(q);
    float mean = s * (1.f / 512.f);
    float var = q * (1.f / 512.f) - mean * mean;
    float inv = rsqrtf(var + LN_EPS);
    size_t base = (size_t)(row0 + r) * CC;
#pragma unroll
    for (int i = 0; i < 8; ++i) {
      float o = (acc[r][i] - mean) * inv * gv[i] + bv[i];
      out[base + i * 64 + lane] = o * sc + x[base + i * 64 + lane];
    }
  }
}

// ---------------------------------------------------------------------------
extern "C" void kernel_launch(void* const* d_in, const int* in_sizes, int n_in,
                              void* d_out, int out_size, void* d_ws,
                              size_t ws_size, hipStream_t stream) {
  const float* x = (const float*)d_in[0];
  const float* Wf = (const float*)d_in[1];
  const float* Wh = (const float*)d_in[2];
  const float* Wo = (const float*)d_in[3];
  const float* gf = (const float*)d_in[4];
  const float* bf = (const float*)d_in[5];
  const float* gh = (const float*)d_in[6];
  const float* bh = (const float*)d_in[7];
  const float* go = (const float*)d_in[8];
  const float* bo = (const float*)d_in[9];
  const float* sc = (const float*)d_in[10];
  float* out = (float*)d_out;

  float* fg = (float*)d_ws;                       // NROWS*CI f32 = 16 MiB
  float* hl = fg + (size_t)NROWS * CI;            // NROWS*CI f32 = 16 MiB

  // K1: 8192 waves (8 rows each) = 2048 blocks of 256
  sgsa_k1_gemm_ln<<<NROWS / (R1 * 4), 256, 0, stream>>>(x, Wf, Wh, gf, bf, gh,
                                                        bh, fg, hl);
  // K2: one block per (b,w)
  sgsa_k2_softmax<<<BB * WW, 256, 0, stream>>>(fg, hl);
  // K3: 8192 waves (8 rows each) = 2048 blocks of 256
  sgsa_k3_gemm_ln_res<<<NROWS / (R3 * 4), 256, 0, stream>>>(hl, Wo, go, bo, sc,
                                                            x, out);
}

// Round 2
// 133.191 us; speedup vs baseline: 1.9612x; 1.9612x over previous
//
#include <hip/hip_runtime.h>
#include <math.h>

// Problem dims (fixed by setup_inputs)
#define BB 16
#define HH 64
#define WW 64
#define CC 512
#define CI 64
#define NROWS (BB * HH * WW)  // 65536 rows of length C
#define LN_EPS 1e-3f

typedef __attribute__((ext_vector_type(8))) short bf16x8;
typedef __attribute__((ext_vector_type(4))) float f32x4;

__device__ __forceinline__ unsigned short f2bf(float f) {
  union {
    float f;
    unsigned int u;
  } v;
  v.f = f;
  unsigned int r = v.u + 0x7FFF + ((v.u >> 16) & 1);  // RNE
  return (unsigned short)(r >> 16);
}

__device__ __forceinline__ float bf2f(unsigned short u) {
  union {
    unsigned int u;
    float f;
  } v;
  v.u = ((unsigned int)u) << 16;
  return v.f;
}

// ---------------------------------------------------------------------------
// Prep: transpose weights to k-contiguous bf16 so MFMA B-fragments are
// contiguous 16B loads. WcT[col][k]: col<64 -> Wf, col in [64,128) -> Wh.
// WoT[col][k]: col<512, k<64 from Wo[k][col].
// ---------------------------------------------------------------------------
__global__ __launch_bounds__(256) void sgsa_prep(
    const float* __restrict__ Wf, const float* __restrict__ Wh,
    const float* __restrict__ Wo, unsigned short* __restrict__ WcT,
    unsigned short* __restrict__ WoT) {
  int tid = blockIdx.x * 256 + threadIdx.x;
  for (int i = tid; i < 128 * 512; i += gridDim.x * 256) {
    int col = i >> 9, k = i & 511;
    float v = (col < 64) ? Wf[k * 64 + col] : Wh[k * 64 + (col - 64)];
    WcT[i] = f2bf(v);
  }
  for (int i = tid; i < 512 * 64; i += gridDim.x * 256) {
    int col = i >> 6, k = i & 63;
    WoT[i] = f2bf(Wo[k * 512 + col]);
  }
}

// ---------------------------------------------------------------------------
// K1 (MFMA): [fg|hl] = LN( x @ [Wf|Wh] ).  M=65536, N=128, K=512, bf16 MFMA
// with fp32 accumulate. One wave computes 32 rows x 128 cols.
// A-frag: lane reads 8 consecutive f32 of its row at k-base (lane>>4)*8,
// converts to bf16.  B-frag: 16B contiguous from WcT.  Same k convention on
// both sides => result invariant to the instruction's internal k mapping.
// D layout (m89-verified): col = lane&15, row = (lane>>4)*4 + reg.
// ---------------------------------------------------------------------------
__global__ __launch_bounds__(256) void sgsa_k1_mfma(
    const float* __restrict__ x, const unsigned short* __restrict__ WcT,
    const float* __restrict__ gf, const float* __restrict__ bf,
    const float* __restrict__ gh, const float* __restrict__ bh,
    float* __restrict__ fg, float* __restrict__ hl) {
  const int lane = threadIdx.x & 63;
  const int wid = blockIdx.x * 4 + (threadIdx.x >> 6);
  const int row0 = wid * 32;
  const int cq = lane & 15;  // A-row-in-tile / B-col-in-tile / D-col
  const int kg = lane >> 4;  // k-group

  f32x4 acc[2][8];
#pragma unroll
  for (int rt = 0; rt < 2; ++rt)
#pragma unroll
    for (int ct = 0; ct < 8; ++ct) acc[rt][ct] = (f32x4){0.f, 0.f, 0.f, 0.f};

  for (int kk = 0; kk < 16; ++kk) {
    const int kb = kk * 32 + kg * 8;
    bf16x8 bfr[8];
#pragma unroll
    for (int ct = 0; ct < 8; ++ct) {
      const int col = ct * 16 + cq;
      bfr[ct] = *(const bf16x8*)&WcT[col * 512 + kb];
    }
#pragma unroll
    for (int rt = 0; rt < 2; ++rt) {
      const float* ap = &x[(size_t)(row0 + rt * 16 + cq) * CC + kb];
      f32x4 a0 = *(const f32x4*)ap;
      f32x4 a1 = *(const f32x4*)(ap + 4);
      bf16x8 af;
#pragma unroll
      for (int j = 0; j < 4; ++j) {
        af[j] = (short)f2bf(a0[j]);
        af[j + 4] = (short)f2bf(a1[j]);
      }
#pragma unroll
      for (int ct = 0; ct < 8; ++ct)
        acc[rt][ct] = __builtin_amdgcn_mfma_f32_16x16x32_bf16(
            af, bfr[ct], acc[rt][ct], 0, 0, 0);
    }
  }

  // LN params per lane: col = ct*16 + cq (f: ct 0..3, h: ct 4..7)
  float gfv[4], bfv[4], ghv[4], bhv[4];
#pragma unroll
  for (int ct = 0; ct < 4; ++ct) {
    gfv[ct] = gf[ct * 16 + cq];
    bfv[ct] = bf[ct * 16 + cq];
    ghv[ct] = gh[ct * 16 + cq];
    bhv[ct] = bh[ct * 16 + cq];
  }

#pragma unroll
  for (int rt = 0; rt < 2; ++rt) {
#pragma unroll
    for (int r = 0; r < 4; ++r) {
      const int row = row0 + rt * 16 + kg * 4 + r;
      // f-branch: ct 0..3
      float s = acc[rt][0][r] + acc[rt][1][r] + acc[rt][2][r] + acc[rt][3][r];
      float q = acc[rt][0][r] * acc[rt][0][r] + acc[rt][1][r] * acc[rt][1][r] +
                acc[rt][2][r] * acc[rt][2][r] + acc[rt][3][r] * acc[rt][3][r];
#pragma unroll
      for (int m = 1; m < 16; m <<= 1) {
        s += __shfl_xor(s, m, 64);
        q += __shfl_xor(q, m, 64);
      }
      float mean = s * (1.f / 64.f);
      float var = q * (1.f / 64.f) - mean * mean;
      float inv = rsqrtf(var + LN_EPS);
#pragma unroll
      for (int ct = 0; ct < 4; ++ct) {
        float v = (acc[rt][ct][r] - mean) * inv * gfv[ct] + bfv[ct];
        fg[(size_t)row * CI + ct * 16 + cq] = v;
      }
      // h-branch: ct 4..7
      float s2 = acc[rt][4][r] + acc[rt][5][r] + acc[rt][6][r] + acc[rt][7][r];
      float q2 = acc[rt][4][r] * acc[rt][4][r] + acc[rt][5][r] * acc[rt][5][r] +
                 acc[rt][6][r] * acc[rt][6][r] + acc[rt][7][r] * acc[rt][7][r];
#pragma unroll
      for (int m = 1; m < 16; m <<= 1) {
        s2 += __shfl_xor(s2, m, 64);
        q2 += __shfl_xor(q2, m, 64);
      }
      float mean2 = s2 * (1.f / 64.f);
      float var2 = q2 * (1.f / 64.f) - mean2 * mean2;
      float inv2 = rsqrtf(var2 + LN_EPS);
#pragma unroll
      for (int ct = 0; ct < 4; ++ct) {
        float v = (acc[rt][ct + 4][r] - mean2) * inv2 * ghv[ct] + bhv[ct];
        hl[(size_t)row * CI + ct * 16 + cq] = v;
      }
    }
  }
}

// ---------------------------------------------------------------------------
// K2: attn = softmax over h of fg[b,w,h,d] * fg[b,h,w,d]; t = attn * hl,
// written in place over hl. One block per (b,w).
// ---------------------------------------------------------------------------
__global__ __launch_bounds__(256) void sgsa_k2_softmax(
    const float* __restrict__ fg, float* __restrict__ hl) {
  const int bw = blockIdx.x;
  const int b = bw >> 6;
  const int w = bw & 63;
  const int d = threadIdx.x & 63;
  const int q = threadIdx.x >> 6;  // 0..3, each owns 16 h values

  float sv[16], hv[16];
#pragma unroll
  for (int i = 0; i < 16; ++i) {
    int h = q * 16 + i;
    float g = fg[(size_t)(((b * 64 + h) * 64 + w) * 64) + d];
    float f = fg[(size_t)(((b * 64 + w) * 64 + h) * 64) + d];
    sv[i] = f * g;
    hv[i] = hl[(size_t)(((b * 64 + h) * 64 + w) * 64) + d];
  }

  __shared__ float red[4][64];

  float m = sv[0];
#pragma unroll
  for (int i = 1; i < 16; ++i) m = fmaxf(m, sv[i]);
  red[q][d] = m;
  __syncthreads();
  m = fmaxf(fmaxf(red[0][d], red[1][d]), fmaxf(red[2][d], red[3][d]));
  __syncthreads();

  float ssum = 0.f;
#pragma unroll
  for (int i = 0; i < 16; ++i) {
    sv[i] = __expf(sv[i] - m);
    ssum += sv[i];
  }
  red[q][d] = ssum;
  __syncthreads();
  ssum = (red[0][d] + red[1][d]) + (red[2][d] + red[3][d]);
  float rinv = 1.f / ssum;

#pragma unroll
  for (int i = 0; i < 16; ++i) {
    int h = q * 16 + i;
    hl[(size_t)(((b * 64 + h) * 64 + w) * 64) + d] = sv[i] * rinv * hv[i];
  }
}

// ---------------------------------------------------------------------------
// K3 (MFMA, split-bf16 on t): out = LN_C(t @ Wo) * scale + x.
// M=65536, N=512, K=64. Block = 4 waves, all on the same 32 rows; wave w owns
// cols w*128 .. w*128+127. t is split t = hi + lo (2 MFMAs) because the final
// LN amplifies GEMM error by 1/row_std.
// ---------------------------------------------------------------------------
__global__ __launch_bounds__(256) void sgsa_k3_mfma(
    const float* __restrict__ t, const unsigned short* __restrict__ WoT,
    const float* __restrict__ go, const float* __restrict__ bo,
    const float* __restrict__ scale, const float* __restrict__ x,
    float* __restrict__ out) {
  const int lane = threadIdx.x & 63;
  const int wv = threadIdx.x >> 6;
  const int row0 = blockIdx.x * 32;
  const int col0 = wv * 128;
  const int cq = lane & 15;
  const int kg = lane >> 4;

  f32x4 acc[2][8];
#pragma unroll
  for (int rt = 0; rt < 2; ++rt)
#pragma unroll
    for (int ct = 0; ct < 8; ++ct) acc[rt][ct] = (f32x4){0.f, 0.f, 0.f, 0.f};

#pragma unroll
  for (int kk = 0; kk < 2; ++kk) {
    const int kb = kk * 32 + kg * 8;
    bf16x8 bfr[8];
#pragma unroll
    for (int ct = 0; ct < 8; ++ct) {
      const int col = col0 + ct * 16 + cq;
      bfr[ct] = *(const bf16x8*)&WoT[col * CI + kb];
    }
#pragma unroll
    for (int rt = 0; rt < 2; ++rt) {
      const float* ap = &t[(size_t)(row0 + rt * 16 + cq) * CI + kb];
      f32x4 a0 = *(const f32x4*)ap;
      f32x4 a1 = *(const f32x4*)(ap + 4);
      bf16x8 ah, al;
#pragma unroll
      for (int j = 0; j < 4; ++j) {
        unsigned short h0 = f2bf(a0[j]);
        unsigned short h1 = f2bf(a1[j]);
        ah[j] = (short)h0;
        ah[j + 4] = (short)h1;
        al[j] = (short)f2bf(a0[j] - bf2f(h0));
        al[j + 4] = (short)f2bf(a1[j] - bf2f(h1));
      }
#pragma unroll
      for (int ct = 0; ct < 8; ++ct) {
        acc[rt][ct] = __builtin_amdgcn_mfma_f32_16x16x32_bf16(
            ah, bfr[ct], acc[rt][ct], 0, 0, 0);
        acc[rt][ct] = __builtin_amdgcn_mfma_f32_16x16x32_bf16(
            al, bfr[ct], acc[rt][ct], 0, 0, 0);
      }
    }
  }

  // Cross-wave LN over C=512: per-row partial sums -> LDS -> combine.
  __shared__ float s_red[4][32];
  __shared__ float q_red[4][32];

  float svv[2][4], qvv[2][4];
#pragma unroll
  for (int rt = 0; rt < 2; ++rt) {
#pragma unroll
    for (int r = 0; r < 4; ++r) {
      float s = 0.f, q = 0.f;
#pragma unroll
      for (int ct = 0; ct < 8; ++ct) {
        float v = acc[rt][ct][r];
        s += v;
        q += v * v;
      }
#pragma unroll
      for (int m = 1; m < 16; m <<= 1) {
        s += __shfl_xor(s, m, 64);
        q += __shfl_xor(q, m, 64);
      }
      svv[rt][r] = s;
      qvv[rt][r] = q;
      if (cq == 0) {
        s_red[wv][rt * 16 + kg * 4 + r] = s;
        q_red[wv][rt * 16 + kg * 4 + r] = q;
      }
    }
  }
  __syncthreads();

  const float sc = scale[0];
  float gov[8], bov[8];
#pragma unroll
  for (int ct = 0; ct < 8; ++ct) {
    gov[ct] = go[col0 + ct * 16 + cq];
    bov[ct] = bo[col0 + ct * 16 + cq];
  }

#pragma unroll
  for (int rt = 0; rt < 2; ++rt) {
#pragma unroll
    for (int r = 0; r < 4; ++r) {
      const int ridx = rt * 16 + kg * 4 + r;
      const int row = row0 + ridx;
      float s = (s_red[0][ridx] + s_red[1][ridx]) +
                (s_red[2][ridx] + s_red[3][ridx]);
      float q = (q_red[0][ridx] + q_red[1][ridx]) +
                (q_red[2][ridx] + q_red[3][ridx]);
      float mean = s * (1.f / 512.f);
      float var = q * (1.f / 512.f) - mean * mean;
      float inv = rsqrtf(var + LN_EPS);
      const size_t base = (size_t)row * CC;
#pragma unroll
      for (int ct = 0; ct < 8; ++ct) {
        const int col = col0 + ct * 16 + cq;
        float o = (acc[rt][ct][r] - mean) * inv * gov[ct] + bov[ct];
        out[base + col] = o * sc + x[base + col];
      }
    }
  }
}

// ---------------------------------------------------------------------------
extern "C" void kernel_launch(void* const* d_in, const int* in_sizes, int n_in,
                              void* d_out, int out_size, void* d_ws,
                              size_t ws_size, hipStream_t stream) {
  const float* x = (const float*)d_in[0];
  const float* Wf = (const float*)d_in[1];
  const float* Wh = (const float*)d_in[2];
  const float* Wo = (const float*)d_in[3];
  const float* gf = (const float*)d_in[4];
  const float* bf = (const float*)d_in[5];
  const float* gh = (const float*)d_in[6];
  const float* bh = (const float*)d_in[7];
  const float* go = (const float*)d_in[8];
  const float* bo = (const float*)d_in[9];
  const float* sc = (const float*)d_in[10];
  float* out = (float*)d_out;

  unsigned short* WcT = (unsigned short*)d_ws;     // 128*512*2 = 128 KiB
  unsigned short* WoT = WcT + 128 * 512;           // 512*64*2  =  64 KiB
  float* fg = (float*)((char*)d_ws + (256 << 10)); // 16 MiB
  float* hl = fg + (size_t)NROWS * CI;             // 16 MiB

  sgsa_prep<<<64, 256, 0, stream>>>(Wf, Wh, Wo, WcT, WoT);
  sgsa_k1_mfma<<<NROWS / 128, 256, 0, stream>>>(x, WcT, gf, bf, gh, bh, fg,
                                                hl);
  sgsa_k2_softmax<<<BB * WW, 256, 0, stream>>>(fg, hl);
  sgsa_k3_mfma<<<NROWS / 32, 256, 0, stream>>>(hl, WoT, go, bo, sc, x, out);
}